// Round 5
// baseline (292.563 us; speedup 1.0000x reference)
//
#include <hip/hip_runtime.h>
#include <math.h>

#define N_NODES 100000
#define N_EDGES 1600000
#define C_IN    128
#define H_DIM   64
#define G_GRAPHS 512
#define MAXG    4096      // max nodes per graph in kA LDS (mean 195, huge margin)
#define E2CAP   524288    // kept-dst edge list cap (expected ~8k)
#define ELCAP   65536     // both-kept edge list cap (expected ~tens)
#define KLCAP   16384     // kept node list cap (math bound ~20/graph)

// lower_bound over sorted batch
__device__ __forceinline__ int lbound(const int* __restrict__ b, int val) {
    int lo = 0, hi = N_NODES;
    while (lo < hi) {
        int mid = (lo + hi) >> 1;
        if (b[mid] < val) lo = mid + 1; else hi = mid;
    }
    return lo;
}

// ---------- fused: graph bounds + raw=x.pool_w + softmax + mask + KL + compaction ----------
__global__ void kA2(const int* __restrict__ batch, const float* __restrict__ x,
                    const float* __restrict__ pool_w, const float* __restrict__ attn,
                    float* __restrict__ sc, unsigned int* __restrict__ kept_bits,
                    int* __restrict__ klist, int* __restrict__ kcount,
                    int* __restrict__ kbase, int* __restrict__ kcnt,
                    float* __restrict__ B, float* __restrict__ out) {
    __shared__ float buf[MAXG];
    __shared__ float red[256];
    __shared__ int   lst[64];
    __shared__ int   cntk;
    __shared__ int   baseS;
    const int g = blockIdx.x;
    const int t = threadIdx.x;
    const int ns = lbound(batch, g);
    const int ne = lbound(batch, g + 1);
    const int cn = ne - ns;
    if (cn <= 0) {
        if (t == 0) { out[G_GRAPHS + g] = 0.f; kbase[g] = 0; kcnt[g] = 0; }
        return;
    }
    // raw phase: 2 rows per wave iter (32 lanes x float4 per row)
    {
        const int lane = t & 63;
        const int w    = t >> 6;          // 0..3
        const int l32  = lane & 31;
        const int half = lane >> 5;
        const float4 pwv = ((const float4*)pool_w)[l32];
        for (int r = w * 2 + half; r < cn; r += 8) {
            float4 xv = ((const float4*)(x + (size_t)(ns + r) * C_IN))[l32];
            float pr = xv.x * pwv.x + xv.y * pwv.y + xv.z * pwv.z + xv.w * pwv.w;
            #pragma unroll
            for (int m = 16; m > 0; m >>= 1) pr += __shfl_xor(pr, m, 64);
            if (l32 == 0) buf[r] = pr;
        }
    }
    __syncthreads();
    // max
    float lmax = -3.4e38f;
    for (int i = t; i < cn; i += 256) lmax = fmaxf(lmax, buf[i]);
    red[t] = lmax; __syncthreads();
    for (int o = 128; o > 0; o >>= 1) { if (t < o) red[t] = fmaxf(red[t], red[t + o]); __syncthreads(); }
    float m = red[0]; __syncthreads();
    // exp + sum
    float lsum = 0.f;
    for (int i = t; i < cn; i += 256) { float e = expf(buf[i] - m); buf[i] = e; lsum += e; }
    red[t] = lsum; __syncthreads();
    for (int o = 128; o > 0; o >>= 1) { if (t < o) red[t] += red[t + o]; __syncthreads(); }
    float z = red[0]; __syncthreads();
    // score + smax
    float lsm = -3.4e38f;
    for (int i = t; i < cn; i += 256) { float s = buf[i] / z; buf[i] = s; lsm = fmaxf(lsm, s); }
    red[t] = lsm; __syncthreads();
    for (int o = 128; o > 0; o >>= 1) { if (t < o) red[t] = fmaxf(red[t], red[t + o]); __syncthreads(); }
    float smax = red[0];
    float thresh = fminf(smax - 1e-7f, 0.05f);
    if (t == 0) cntk = 0;
    __syncthreads();
    // kept compaction + KL (score written to global only for kept nodes)
    float klacc = 0.f;
    for (int i = t; i < cn; i += 256) {
        float s = buf[i];
        if (s > thresh) {
            int n = ns + i;
            int p = atomicAdd(&cntk, 1);
            if (p < 64) lst[p] = i;
            sc[n] = s;
            float a = attn[n];
            klacc += a * (logf(a) - logf(s + 1e-14f));
        }
    }
    red[t] = klacc; __syncthreads();
    for (int o = 128; o > 0; o >>= 1) { if (t < o) red[t] += red[t + o]; __syncthreads(); }
    int kc = cntk;
    int kcc = kc < 64 ? kc : 64;
    if (t == 0) {
        out[G_GRAPHS + g] = (kc > 0) ? red[0] / (float)kc : 0.f;
        baseS = (kcc > 0) ? atomicAdd(kcount, kcc) : 0;
        kbase[g] = baseS;
        kcnt[g]  = kcc;
    }
    __syncthreads();
    int base = baseS;
    for (int i = t; i < kcc; i += 256) {
        int n = ns + lst[i];
        if (base + i < KLCAP) klist[base + i] = n;
        atomicOr(&kept_bits[n >> 5], 1u << (n & 31));
    }
    __syncthreads();
    for (int j = t; j < kcc * H_DIM; j += 256)
        B[(size_t)(ns + lst[j >> 6]) * H_DIM + (j & 63)] = 0.f;
}

// wave-ballot list emit: one global atomic per wave-with-hits
__device__ __forceinline__ void emit(bool hit, int s, int d, int* __restrict__ list,
                                     int cap, int* __restrict__ count, int lane) {
    unsigned long long bal = __ballot(hit);
    if (bal == 0ull) return;
    int leader = __ffsll((long long)bal) - 1;
    int cnt = __popcll(bal);
    int base = 0;
    if (lane == leader) base = atomicAdd(count, cnt);
    base = __shfl(base, leader, 64);
    if (hit) {
        int p = base + __popcll(bal & ((1ull << lane) - 1ull));
        if (p < cap) { list[p] = s; list[cap + p] = d; }
    }
}

// ---------- edge scan: 4 edges/thread, int4 loads, no LDS, no barriers ----------
__global__ void k5a2(const int* __restrict__ ei, const unsigned int* __restrict__ bits,
                     int* __restrict__ e2sd, int* __restrict__ e2count,
                     int* __restrict__ elsd, int* __restrict__ elcount) {
    const int lane = threadIdx.x & 63;
    int t4 = blockIdx.x * blockDim.x + threadIdx.x;
    bool valid = t4 < (N_EDGES / 4);
    int4 s4 = make_int4(0, 0, 0, 0), d4 = make_int4(0, 0, 0, 0);
    if (valid) {
        s4 = ((const int4*)ei)[t4];
        d4 = ((const int4*)(ei + N_EDGES))[t4];
    }
    #define KD(dd) (valid && (((bits[(dd) >> 5] >> ((dd) & 31)) & 1u) != 0u))
    bool k0 = KD(d4.x), k1 = KD(d4.y), k2 = KD(d4.z), k3 = KD(d4.w);
    bool b0 = k0 && (((bits[s4.x >> 5] >> (s4.x & 31)) & 1u) != 0u);
    bool b1 = k1 && (((bits[s4.y >> 5] >> (s4.y & 31)) & 1u) != 0u);
    bool b2 = k2 && (((bits[s4.z >> 5] >> (s4.z & 31)) & 1u) != 0u);
    bool b3 = k3 && (((bits[s4.w >> 5] >> (s4.w & 31)) & 1u) != 0u);
    #undef KD
    emit(k0, s4.x, d4.x, e2sd, E2CAP, e2count, lane);
    emit(k1, s4.y, d4.y, e2sd, E2CAP, e2count, lane);
    emit(k2, s4.z, d4.z, e2sd, E2CAP, e2count, lane);
    emit(k3, s4.w, d4.w, e2sd, E2CAP, e2count, lane);
    emit(b0, s4.x, d4.x, elsd, ELCAP, elcount, lane);
    emit(b1, s4.y, d4.y, elsd, ELCAP, elcount, lane);
    emit(b2, s4.z, d4.z, elsd, ELCAP, elcount, lane);
    emit(b3, s4.w, d4.w, elsd, ELCAP, elcount, lane);
}

// ---------- layer-1 agg for kept-dst edges: B[dst] += x[src]@W1 ----------
__global__ void k5b(const int* __restrict__ e2sd, const int* __restrict__ e2count,
                    const float* __restrict__ x, const float* __restrict__ W1,
                    float* __restrict__ B) {
    __shared__ float W1s[C_IN * H_DIM];
    for (int i = threadIdx.x; i < C_IN * H_DIM; i += blockDim.x) W1s[i] = W1[i];
    __syncthreads();
    const int lane = threadIdx.x & 63;
    const int wid  = blockIdx.x * (blockDim.x >> 6) + (threadIdx.x >> 6);
    const int nw   = gridDim.x * (blockDim.x >> 6);
    int ec = *e2count; if (ec > E2CAP) ec = E2CAP;
    for (int idx = wid; idx < ec; idx += nw) {
        int s = __builtin_amdgcn_readfirstlane(e2sd[idx]);
        int d = __builtin_amdgcn_readfirstlane(e2sd[E2CAP + idx]);
        const float4* xr = (const float4*)(x + (size_t)s * C_IN);
        float acc = 0.f;
        #pragma unroll 8
        for (int k4 = 0; k4 < C_IN / 4; ++k4) {
            float4 xv = xr[k4];
            acc = fmaf(xv.x, W1s[(4 * k4 + 0) * H_DIM + lane], acc);
            acc = fmaf(xv.y, W1s[(4 * k4 + 1) * H_DIM + lane], acc);
            acc = fmaf(xv.z, W1s[(4 * k4 + 2) * H_DIM + lane], acc);
            acc = fmaf(xv.w, W1s[(4 * k4 + 3) * H_DIM + lane], acc);
        }
        atomicAdd(&B[(size_t)d * H_DIM + lane], acc);
    }
}

// ---------- kept nodes: layer-1 MLP + W3 projection ----------
__global__ void k6_kept(const int* __restrict__ klist, const int* __restrict__ kcount,
                        const float* __restrict__ sc, const float* __restrict__ x,
                        const float* __restrict__ W1,
                        const float* __restrict__ b1, const float* __restrict__ W2,
                        const float* __restrict__ b2, const float* __restrict__ W3,
                        float* __restrict__ A, float* __restrict__ B) {
    __shared__ float W1s[C_IN * H_DIM];
    __shared__ float W2s[H_DIM * H_DIM];
    __shared__ float W3s[H_DIM * H_DIM];
    for (int i = threadIdx.x; i < C_IN * H_DIM; i += blockDim.x) W1s[i] = W1[i];
    for (int i = threadIdx.x; i < H_DIM * H_DIM; i += blockDim.x) {
        W2s[i] = W2[i];
        W3s[i] = W3[i];
    }
    __syncthreads();
    const int lane = threadIdx.x & 63;
    const int wid  = blockIdx.x * (blockDim.x >> 6) + (threadIdx.x >> 6);
    const int nw   = gridDim.x * (blockDim.x >> 6);
    int kc = *kcount; if (kc > KLCAP) kc = KLCAP;
    const float b1l = b1[lane], b2l = b2[lane];
    for (int idx = wid; idx < kc; idx += nw) {
        int n = __builtin_amdgcn_readfirstlane(klist[idx]);
        const float4* xr = (const float4*)(x + (size_t)n * C_IN);
        float u = 0.f;
        #pragma unroll 8
        for (int k4 = 0; k4 < C_IN / 4; ++k4) {
            float4 xv = xr[k4];
            u = fmaf(xv.x, W1s[(4 * k4 + 0) * H_DIM + lane], u);
            u = fmaf(xv.y, W1s[(4 * k4 + 1) * H_DIM + lane], u);
            u = fmaf(xv.z, W1s[(4 * k4 + 2) * H_DIM + lane], u);
            u = fmaf(xv.w, W1s[(4 * k4 + 3) * H_DIM + lane], u);
        }
        float t1 = fmaxf(u + B[(size_t)n * H_DIM + lane] + b1l, 0.f);
        B[(size_t)n * H_DIM + lane] = 0.f;  // reset for layer-2 agg
        float o1 = b2l;
        #pragma unroll 8
        for (int k = 0; k < H_DIM; ++k) o1 = fmaf(__shfl(t1, k, 64), W2s[k * H_DIM + lane], o1);
        o1 = fmaxf(o1, 0.f);
        float v = 0.f;
        #pragma unroll 8
        for (int k = 0; k < H_DIM; ++k) v = fmaf(__shfl(o1, k, 64), W3s[k * H_DIM + lane], v);
        A[(size_t)n * H_DIM + lane] = v * sc[n];
    }
}

// ---------- layer-2 agg over both-kept edges ----------
__global__ void k7_scatter2(const int* __restrict__ elsd, const int* __restrict__ elcount,
                            const float* __restrict__ A, float* __restrict__ B) {
    const int lane = threadIdx.x & 63;
    const int wid  = blockIdx.x * (blockDim.x >> 6) + (threadIdx.x >> 6);
    const int nw   = gridDim.x * (blockDim.x >> 6);
    int ec = *elcount; if (ec > ELCAP) ec = ELCAP;
    for (int idx = wid; idx < ec; idx += nw) {
        int s = __builtin_amdgcn_readfirstlane(elsd[idx]);
        int d = __builtin_amdgcn_readfirstlane(elsd[ELCAP + idx]);
        atomicAdd(&B[(size_t)d * H_DIM + lane], A[(size_t)s * H_DIM + lane]);
    }
}

// ---------- per-graph: layer-2 MLP + pool + pred + ratio ----------
__global__ void k8b(const int* __restrict__ klist, const int* __restrict__ kbase,
                    const int* __restrict__ kcnt, const int* __restrict__ kcount,
                    const float* __restrict__ b3, const float* __restrict__ W4,
                    const float* __restrict__ b4, const float* __restrict__ Wl,
                    const float* __restrict__ bl,
                    const float* __restrict__ A, const float* __restrict__ B,
                    float* __restrict__ out) {
    const int g = blockIdx.x;
    const int lane = threadIdx.x;  // 64 threads
    const float b3l = b3[lane], b4l = b4[lane];
    const int kc = kcnt[g];
    const int base = kbase[g];
    float gsum = 0.f;
    for (int i = 0; i < kc; ++i) {
        int n = __builtin_amdgcn_readfirstlane(klist[base + i]);
        float t = fmaxf(A[(size_t)n * H_DIM + lane] + B[(size_t)n * H_DIM + lane] + b3l, 0.f);
        float o2 = b4l;
        #pragma unroll 8
        for (int k = 0; k < H_DIM; ++k) o2 = fmaf(__shfl(t, k, 64), W4[k * H_DIM + lane], o2);
        gsum += fmaxf(o2, 0.f);
    }
    float p = gsum * Wl[lane];
    #pragma unroll
    for (int m = 32; m > 0; m >>= 1) p += __shfl_xor(p, m, 64);
    if (lane == 0) {
        out[g] = p + bl[0];
        if (g == 0) out[2 * G_GRAPHS] = (float)(*kcount) * (1.f / (float)N_NODES);
    }
}

extern "C" void kernel_launch(void* const* d_in, const int* in_sizes, int n_in,
                              void* d_out, int out_size, void* d_ws, size_t ws_size,
                              hipStream_t stream) {
    const float* x      = (const float*)d_in[0];
    const int*   ei     = (const int*)d_in[1];
    const int*   batch  = (const int*)d_in[2];
    const float* attn   = (const float*)d_in[3];
    const float* W1     = (const float*)d_in[4];
    const float* b1     = (const float*)d_in[5];
    const float* W2     = (const float*)d_in[6];
    const float* b2     = (const float*)d_in[7];
    const float* pool_w = (const float*)d_in[8];
    const float* W3     = (const float*)d_in[9];
    const float* b3     = (const float*)d_in[10];
    const float* W4     = (const float*)d_in[11];
    const float* b4     = (const float*)d_in[12];
    const float* Wl     = (const float*)d_in[13];
    const float* bl     = (const float*)d_in[14];
    float* out = (float*)d_out;

    // workspace layout
    float* A      = (float*)d_ws;                       // N*64 (kept rows only used)
    float* B      = A + (size_t)N_NODES * H_DIM;        // N*64 (kept rows only used)
    float* sc     = B + (size_t)N_NODES * H_DIM;        // N (kept scores only)
    int*   klist  = (int*)(sc + N_NODES);               // KLCAP
    int*   kbase  = klist + KLCAP;                      // G
    int*   kcnt   = kbase + G_GRAPHS;                   // G
    int*   e2sd   = kcnt + G_GRAPHS;                    // 2*E2CAP
    int*   elsd   = e2sd + 2 * E2CAP;                   // 2*ELCAP
    // zeroed block:
    unsigned int* kept_bits = (unsigned int*)(elsd + 2 * ELCAP);   // ceil(N/32)=3125 -> 3136
    int*          kcount    = (int*)(kept_bits + 3136);
    int*          e2count   = kcount + 1;
    int*          elcount   = e2count + 1;
    size_t zero_bytes = (size_t)((char*)(elcount + 1) - (char*)kept_bits);

    hipMemsetAsync(kept_bits, 0, zero_bytes, stream);

    kA2  <<<G_GRAPHS, 256, 0, stream>>>(batch, x, pool_w, attn, sc, kept_bits,
                                        klist, kcount, kbase, kcnt, B, out);
    k5a2 <<<(N_EDGES / 4 + 255) / 256, 256, 0, stream>>>(ei, kept_bits, e2sd, e2count,
                                                         elsd, elcount);
    k5b  <<<256, 256, 0, stream>>>(e2sd, e2count, x, W1, B);
    k6_kept<<<64, 256, 0, stream>>>(klist, kcount, sc, x, W1, b1, W2, b2, W3, A, B);
    k7_scatter2<<<32, 256, 0, stream>>>(elsd, elcount, A, B);
    k8b  <<<G_GRAPHS, 64, 0, stream>>>(klist, kbase, kcnt, kcount, b3, W4, b4, Wl, bl,
                                       A, B, out);
}

// Round 6
// 289.863 us; speedup vs baseline: 1.0093x; 1.0093x over previous
//
#include <hip/hip_runtime.h>
#include <math.h>

#define N_NODES 100000
#define N_EDGES 1600000
#define C_IN    128
#define H_DIM   64
#define G_GRAPHS 512
#define MAXG    4096      // max nodes/graph in kA3 LDS (mean 195, 5-sigma max ~265)
#define ELCAP   65536     // both-kept edge list cap (expected ~tens)
#define KPG     32        // kept-per-graph cap (math bound: scores sum to 1, thresh 0.05 -> <=19)

// lower_bound over sorted batch
__device__ __forceinline__ int lbound(const int* __restrict__ b, int val) {
    int lo = 0, hi = N_NODES;
    while (lo < hi) {
        int mid = (lo + hi) >> 1;
        if (b[mid] < val) lo = mid + 1; else hi = mid;
    }
    return lo;
}

// ---------- raw = x . pool_w (pure BW, wide grid, no atomics) ----------
__global__ void kraw(const float* __restrict__ x, const float* __restrict__ pool_w,
                     float* __restrict__ sc) {
    const int lane = threadIdx.x & 63;
    const int l32  = lane & 31;
    const int half = lane >> 5;
    const float4 pwv = ((const float4*)pool_w)[l32];
    const int wid = blockIdx.x * (blockDim.x >> 6) + (threadIdx.x >> 6);
    const int nw  = gridDim.x * (blockDim.x >> 6);
    for (int r0 = wid * 2; r0 < N_NODES; r0 += nw * 2) {
        int row = r0 + half;  // N even, r0 even => row < N
        float4 xv = ((const float4*)(x + (size_t)row * C_IN))[l32];
        float pr = xv.x * pwv.x + xv.y * pwv.y + xv.z * pwv.z + xv.w * pwv.w;
        #pragma unroll
        for (int m = 16; m > 0; m >>= 1) pr += __shfl_xor(pr, m, 64);
        if (l32 == 0) sc[row] = pr;
    }
}

// ---------- per-graph softmax + mask + KL + per-graph-strided compaction ----------
__global__ void kA3(const int* __restrict__ batch, const float* __restrict__ attn,
                    float* __restrict__ sc, unsigned int* __restrict__ kept_bits,
                    int* __restrict__ klist, int* __restrict__ kcnt,
                    float* __restrict__ B, float* __restrict__ out) {
    __shared__ float buf[MAXG];
    __shared__ float red[256];
    __shared__ int   lst[KPG];
    __shared__ int   cntk;
    const int g = blockIdx.x;
    const int t = threadIdx.x;
    const int ns = lbound(batch, g);
    const int ne = lbound(batch, g + 1);
    const int cn = ne - ns;
    if (cn <= 0) {
        if (t == 0) { out[G_GRAPHS + g] = 0.f; kcnt[g] = 0; }
        return;
    }
    if (t == 0) cntk = 0;
    // load raw, local max
    float lmax = -3.4e38f;
    for (int i = t; i < cn; i += 256) { float r = sc[ns + i]; buf[i] = r; lmax = fmaxf(lmax, r); }
    red[t] = lmax; __syncthreads();
    for (int o = 128; o > 0; o >>= 1) { if (t < o) red[t] = fmaxf(red[t], red[t + o]); __syncthreads(); }
    float m = red[0]; __syncthreads();
    // exp + sum
    float lsum = 0.f;
    for (int i = t; i < cn; i += 256) { float e = expf(buf[i] - m); buf[i] = e; lsum += e; }
    red[t] = lsum; __syncthreads();
    for (int o = 128; o > 0; o >>= 1) { if (t < o) red[t] += red[t + o]; __syncthreads(); }
    float z = red[0]; __syncthreads();
    // score + smax
    float lsm = -3.4e38f;
    for (int i = t; i < cn; i += 256) { float s = buf[i] / z; buf[i] = s; lsm = fmaxf(lsm, s); }
    red[t] = lsm; __syncthreads();
    for (int o = 128; o > 0; o >>= 1) { if (t < o) red[t] = fmaxf(red[t], red[t + o]); __syncthreads(); }
    float smax = red[0];
    float thresh = fminf(smax - 1e-7f, 0.05f);
    __syncthreads();
    // kept compaction (LDS) + KL; write score to global only for kept
    float klacc = 0.f;
    for (int i = t; i < cn; i += 256) {
        float s = buf[i];
        if (s > thresh) {
            int n = ns + i;
            int p = atomicAdd(&cntk, 1);
            if (p < KPG) lst[p] = i;
            sc[n] = s;
            float a = attn[n];
            klacc += a * (logf(a) - logf(s + 1e-14f));
        }
    }
    red[t] = klacc; __syncthreads();
    for (int o = 128; o > 0; o >>= 1) { if (t < o) red[t] += red[t + o]; __syncthreads(); }
    int kc = cntk;
    int kcc = kc < KPG ? kc : KPG;
    if (t == 0) {
        out[G_GRAPHS + g] = (kc > 0) ? red[0] / (float)kc : 0.f;
        kcnt[g] = kcc;
    }
    for (int i = t; i < kcc; i += 256) {
        int n = ns + lst[i];
        klist[g * KPG + i] = n;
        atomicOr(&kept_bits[n >> 5], 1u << (n & 31));
    }
    __syncthreads();
    for (int j = t; j < kcc * H_DIM; j += 256)
        B[(size_t)(ns + lst[j >> 6]) * H_DIM + (j & 63)] = 0.f;
}

// wave-ballot list emit: one global atomic per wave-with-hits (used only for rare both-kept)
__device__ __forceinline__ void emit(bool hit, int s, int d, int* __restrict__ list,
                                     int cap, int* __restrict__ count, int lane) {
    unsigned long long bal = __ballot(hit);
    if (bal == 0ull) return;
    int leader = __ffsll((long long)bal) - 1;
    int cnt = __popcll(bal);
    int base = 0;
    if (lane == leader) base = atomicAdd(count, cnt);
    base = __shfl(base, leader, 64);
    if (hit) {
        int p = base + __popcll(bal & ((1ull << lane) - 1ull));
        if (p < cap) { list[p] = s; list[cap + p] = d; }
    }
}

// ---------- fused edge scan + layer-1 agg: block-local compaction, in-block consume ----------
// 1024 edges/block; kept-dst hits stay in LDS; B[dst] += x[src]@W1 computed in-block.
__global__ void k5f(const int* __restrict__ ei, const unsigned int* __restrict__ bits,
                    const float* __restrict__ x, const float* __restrict__ W1,
                    float* __restrict__ B, int* __restrict__ elsd,
                    int* __restrict__ elcount) {
    __shared__ float W1s[C_IN * H_DIM];   // 32 KB
    __shared__ int ls[1024], ld[1024];    // 8 KB
    __shared__ int c1;
    const int t = threadIdx.x;
    const int lane = t & 63;
    // stage W1 (independent of detection)
    for (int i = t; i < C_IN * H_DIM; i += 256) W1s[i] = W1[i];
    if (t == 0) c1 = 0;
    __syncthreads();
    // detection: 4 edges/thread via int4
    int t4 = blockIdx.x * 256 + t;
    bool valid = t4 < (N_EDGES / 4);
    int4 s4 = make_int4(0, 0, 0, 0), d4 = make_int4(0, 0, 0, 0);
    if (valid) {
        s4 = ((const int4*)ei)[t4];
        d4 = ((const int4*)(ei + N_EDGES))[t4];
    }
    int sv[4] = {s4.x, s4.y, s4.z, s4.w};
    int dv[4] = {d4.x, d4.y, d4.z, d4.w};
    bool bk[4];
    #pragma unroll
    for (int q = 0; q < 4; ++q) {
        int ss = sv[q], dd = dv[q];
        bool kd = valid && (((bits[dd >> 5] >> (dd & 31)) & 1u) != 0u);
        bk[q] = kd && (((bits[ss >> 5] >> (ss & 31)) & 1u) != 0u);
        if (kd) { int p = atomicAdd(&c1, 1); ls[p] = ss; ld[p] = dd; }
    }
    #pragma unroll
    for (int q = 0; q < 4; ++q) emit(bk[q], sv[q], dv[q], elsd, ELCAP, elcount, lane);
    __syncthreads();
    // consume: wave per hit-edge, lane = output channel
    const int w = t >> 6;
    const int nloc = c1;
    for (int idx = w; idx < nloc; idx += 4) {
        int s = ls[idx];
        int d = ld[idx];
        const float4* xr = (const float4*)(x + (size_t)s * C_IN);
        float acc = 0.f;
        #pragma unroll 8
        for (int k4 = 0; k4 < C_IN / 4; ++k4) {
            float4 xv = xr[k4];
            acc = fmaf(xv.x, W1s[(4 * k4 + 0) * H_DIM + lane], acc);
            acc = fmaf(xv.y, W1s[(4 * k4 + 1) * H_DIM + lane], acc);
            acc = fmaf(xv.z, W1s[(4 * k4 + 2) * H_DIM + lane], acc);
            acc = fmaf(xv.w, W1s[(4 * k4 + 3) * H_DIM + lane], acc);
        }
        atomicAdd(&B[(size_t)d * H_DIM + lane], acc);
    }
}

// ---------- kept nodes (slot-strided): layer-1 MLP + W3 projection ----------
__global__ void k6_kept(const int* __restrict__ klist, const int* __restrict__ kcnt,
                        const float* __restrict__ sc, const float* __restrict__ x,
                        const float* __restrict__ W1,
                        const float* __restrict__ b1, const float* __restrict__ W2,
                        const float* __restrict__ b2, const float* __restrict__ W3,
                        float* __restrict__ A, float* __restrict__ B) {
    __shared__ float W1s[C_IN * H_DIM];
    __shared__ float W2s[H_DIM * H_DIM];
    __shared__ float W3s[H_DIM * H_DIM];
    for (int i = threadIdx.x; i < C_IN * H_DIM; i += blockDim.x) W1s[i] = W1[i];
    for (int i = threadIdx.x; i < H_DIM * H_DIM; i += blockDim.x) {
        W2s[i] = W2[i];
        W3s[i] = W3[i];
    }
    __syncthreads();
    const int lane = threadIdx.x & 63;
    const int wid  = blockIdx.x * (blockDim.x >> 6) + (threadIdx.x >> 6);
    const int nw   = gridDim.x * (blockDim.x >> 6);
    const float b1l = b1[lane], b2l = b2[lane];
    for (int slot = wid; slot < G_GRAPHS * KPG; slot += nw) {
        int g = slot / KPG;
        int i = slot - g * KPG;
        if (i >= kcnt[g]) continue;
        int n = __builtin_amdgcn_readfirstlane(klist[slot]);
        const float4* xr = (const float4*)(x + (size_t)n * C_IN);
        float u = 0.f;
        #pragma unroll 8
        for (int k4 = 0; k4 < C_IN / 4; ++k4) {
            float4 xv = xr[k4];
            u = fmaf(xv.x, W1s[(4 * k4 + 0) * H_DIM + lane], u);
            u = fmaf(xv.y, W1s[(4 * k4 + 1) * H_DIM + lane], u);
            u = fmaf(xv.z, W1s[(4 * k4 + 2) * H_DIM + lane], u);
            u = fmaf(xv.w, W1s[(4 * k4 + 3) * H_DIM + lane], u);
        }
        float t1 = fmaxf(u + B[(size_t)n * H_DIM + lane] + b1l, 0.f);
        B[(size_t)n * H_DIM + lane] = 0.f;  // reset for layer-2 agg
        float o1 = b2l;
        #pragma unroll 8
        for (int k = 0; k < H_DIM; ++k) o1 = fmaf(__shfl(t1, k, 64), W2s[k * H_DIM + lane], o1);
        o1 = fmaxf(o1, 0.f);
        float v = 0.f;
        #pragma unroll 8
        for (int k = 0; k < H_DIM; ++k) v = fmaf(__shfl(o1, k, 64), W3s[k * H_DIM + lane], v);
        A[(size_t)n * H_DIM + lane] = v * sc[n];
    }
}

// ---------- layer-2 agg over both-kept edges ----------
__global__ void k7_scatter2(const int* __restrict__ elsd, const int* __restrict__ elcount,
                            const float* __restrict__ A, float* __restrict__ B) {
    const int lane = threadIdx.x & 63;
    const int wid  = blockIdx.x * (blockDim.x >> 6) + (threadIdx.x >> 6);
    const int nw   = gridDim.x * (blockDim.x >> 6);
    int ec = *elcount; if (ec > ELCAP) ec = ELCAP;
    for (int idx = wid; idx < ec; idx += nw) {
        int s = __builtin_amdgcn_readfirstlane(elsd[idx]);
        int d = __builtin_amdgcn_readfirstlane(elsd[ELCAP + idx]);
        atomicAdd(&B[(size_t)d * H_DIM + lane], A[(size_t)s * H_DIM + lane]);
    }
}

// ---------- per-graph: layer-2 MLP + pool + pred + ratio ----------
__global__ void k8b(const int* __restrict__ klist, const int* __restrict__ kcnt,
                    const float* __restrict__ b3, const float* __restrict__ W4,
                    const float* __restrict__ b4, const float* __restrict__ Wl,
                    const float* __restrict__ bl,
                    const float* __restrict__ A, const float* __restrict__ B,
                    float* __restrict__ out) {
    const int g = blockIdx.x;
    const int lane = threadIdx.x;  // 64 threads
    const float b3l = b3[lane], b4l = b4[lane];
    const int kc = kcnt[g];
    float gsum = 0.f;
    for (int i = 0; i < kc; ++i) {
        int n = __builtin_amdgcn_readfirstlane(klist[g * KPG + i]);
        float t = fmaxf(A[(size_t)n * H_DIM + lane] + B[(size_t)n * H_DIM + lane] + b3l, 0.f);
        float o2 = b4l;
        #pragma unroll 8
        for (int k = 0; k < H_DIM; ++k) o2 = fmaf(__shfl(t, k, 64), W4[k * H_DIM + lane], o2);
        gsum += fmaxf(o2, 0.f);
    }
    float p = gsum * Wl[lane];
    #pragma unroll
    for (int m = 32; m > 0; m >>= 1) p += __shfl_xor(p, m, 64);
    if (lane == 0) out[g] = p + bl[0];
    if (g == 0) {
        int tot = 0;
        for (int i = lane; i < G_GRAPHS; i += 64) tot += kcnt[i];
        #pragma unroll
        for (int m = 32; m > 0; m >>= 1) tot += __shfl_xor(tot, m, 64);
        if (lane == 0) out[2 * G_GRAPHS] = (float)tot * (1.f / (float)N_NODES);
    }
}

extern "C" void kernel_launch(void* const* d_in, const int* in_sizes, int n_in,
                              void* d_out, int out_size, void* d_ws, size_t ws_size,
                              hipStream_t stream) {
    const float* x      = (const float*)d_in[0];
    const int*   ei     = (const int*)d_in[1];
    const int*   batch  = (const int*)d_in[2];
    const float* attn   = (const float*)d_in[3];
    const float* W1     = (const float*)d_in[4];
    const float* b1     = (const float*)d_in[5];
    const float* W2     = (const float*)d_in[6];
    const float* b2     = (const float*)d_in[7];
    const float* pool_w = (const float*)d_in[8];
    const float* W3     = (const float*)d_in[9];
    const float* b3     = (const float*)d_in[10];
    const float* W4     = (const float*)d_in[11];
    const float* b4     = (const float*)d_in[12];
    const float* Wl     = (const float*)d_in[13];
    const float* bl     = (const float*)d_in[14];
    float* out = (float*)d_out;

    // workspace layout
    float* A      = (float*)d_ws;                       // N*64 (kept rows only used)
    float* B      = A + (size_t)N_NODES * H_DIM;        // N*64 (kept rows only used)
    float* sc     = B + (size_t)N_NODES * H_DIM;        // N: raw -> kept scores
    int*   klist  = (int*)(sc + N_NODES);               // G*KPG (per-graph strided)
    int*   kcnt   = klist + G_GRAPHS * KPG;             // G
    int*   elsd   = kcnt + G_GRAPHS;                    // 2*ELCAP
    // zeroed block:
    unsigned int* kept_bits = (unsigned int*)(elsd + 2 * ELCAP);   // ceil(N/32)=3125 -> 3136
    int*          elcount   = (int*)(kept_bits + 3136);
    size_t zero_bytes = (size_t)((char*)(elcount + 1) - (char*)kept_bits);

    hipMemsetAsync(kept_bits, 0, zero_bytes, stream);

    kraw <<<2048, 256, 0, stream>>>(x, pool_w, sc);
    kA3  <<<G_GRAPHS, 256, 0, stream>>>(batch, attn, sc, kept_bits, klist, kcnt, B, out);
    k5f  <<<(N_EDGES / 4 + 255) / 256, 256, 0, stream>>>(ei, kept_bits, x, W1, B,
                                                         elsd, elcount);
    k6_kept<<<128, 256, 0, stream>>>(klist, kcnt, sc, x, W1, b1, W2, b2, W3, A, B);
    k7_scatter2<<<32, 256, 0, stream>>>(elsd, elcount, A, B);
    k8b  <<<G_GRAPHS, 64, 0, stream>>>(klist, kcnt, b3, W4, b4, Wl, bl, A, B, out);
}

// Round 7
// 183.803 us; speedup vs baseline: 1.5917x; 1.5770x over previous
//
#include <hip/hip_runtime.h>
#include <math.h>

#define N_NODES 100000
#define N_EDGES 1600000
#define C_IN    128
#define H_DIM   64
#define G_GRAPHS 512
#define MAXG    4096      // max nodes/graph in kA3 LDS (mean 195, huge margin)
#define ELCAP   65536     // both-kept edge list cap (expected ~tens)
#define KPG     32        // kept-per-graph cap (math bound: scores sum to 1, thresh 0.05 -> <=19)

// lower_bound over sorted batch
__device__ __forceinline__ int lbound(const int* __restrict__ b, int val) {
    int lo = 0, hi = N_NODES;
    while (lo < hi) {
        int mid = (lo + hi) >> 1;
        if (b[mid] < val) lo = mid + 1; else hi = mid;
    }
    return lo;
}

// ---------- raw = x . pool_w (pure BW, wide grid, no atomics) ----------
__global__ void kraw(const float* __restrict__ x, const float* __restrict__ pool_w,
                     float* __restrict__ sc) {
    const int lane = threadIdx.x & 63;
    const int l32  = lane & 31;
    const int half = lane >> 5;
    const float4 pwv = ((const float4*)pool_w)[l32];
    const int wid = blockIdx.x * (blockDim.x >> 6) + (threadIdx.x >> 6);
    const int nw  = gridDim.x * (blockDim.x >> 6);
    for (int r0 = wid * 2; r0 < N_NODES; r0 += nw * 2) {
        int row = r0 + half;  // N even, r0 even => row < N
        float4 xv = ((const float4*)(x + (size_t)row * C_IN))[l32];
        float pr = xv.x * pwv.x + xv.y * pwv.y + xv.z * pwv.z + xv.w * pwv.w;
        #pragma unroll
        for (int m = 16; m > 0; m >>= 1) pr += __shfl_xor(pr, m, 64);
        if (l32 == 0) sc[row] = pr;
    }
}

// ---------- per-graph softmax + mask + KL + per-graph-strided compaction ----------
__global__ void kA3(const int* __restrict__ batch, const float* __restrict__ attn,
                    float* __restrict__ sc, unsigned int* __restrict__ kept_bits,
                    int* __restrict__ klist, int* __restrict__ kcnt,
                    float* __restrict__ B, float* __restrict__ out) {
    __shared__ float buf[MAXG];
    __shared__ float red[256];
    __shared__ int   lst[KPG];
    __shared__ int   cntk;
    const int g = blockIdx.x;
    const int t = threadIdx.x;
    const int ns = lbound(batch, g);
    const int ne = lbound(batch, g + 1);
    const int cn = ne - ns;
    if (cn <= 0) {
        if (t == 0) { out[G_GRAPHS + g] = 0.f; kcnt[g] = 0; }
        return;
    }
    if (t == 0) cntk = 0;
    // load raw, local max
    float lmax = -3.4e38f;
    for (int i = t; i < cn; i += 256) { float r = sc[ns + i]; buf[i] = r; lmax = fmaxf(lmax, r); }
    red[t] = lmax; __syncthreads();
    for (int o = 128; o > 0; o >>= 1) { if (t < o) red[t] = fmaxf(red[t], red[t + o]); __syncthreads(); }
    float m = red[0]; __syncthreads();
    // exp + sum
    float lsum = 0.f;
    for (int i = t; i < cn; i += 256) { float e = expf(buf[i] - m); buf[i] = e; lsum += e; }
    red[t] = lsum; __syncthreads();
    for (int o = 128; o > 0; o >>= 1) { if (t < o) red[t] += red[t + o]; __syncthreads(); }
    float z = red[0]; __syncthreads();
    // score + smax
    float lsm = -3.4e38f;
    for (int i = t; i < cn; i += 256) { float s = buf[i] / z; buf[i] = s; lsm = fmaxf(lsm, s); }
    red[t] = lsm; __syncthreads();
    for (int o = 128; o > 0; o >>= 1) { if (t < o) red[t] = fmaxf(red[t], red[t + o]); __syncthreads(); }
    float smax = red[0];
    float thresh = fminf(smax - 1e-7f, 0.05f);
    __syncthreads();
    // kept compaction (LDS) + KL; write score to global only for kept
    float klacc = 0.f;
    for (int i = t; i < cn; i += 256) {
        float s = buf[i];
        if (s > thresh) {
            int n = ns + i;
            int p = atomicAdd(&cntk, 1);
            if (p < KPG) lst[p] = i;
            sc[n] = s;
            float a = attn[n];
            klacc += a * (logf(a) - logf(s + 1e-14f));
        }
    }
    red[t] = klacc; __syncthreads();
    for (int o = 128; o > 0; o >>= 1) { if (t < o) red[t] += red[t + o]; __syncthreads(); }
    int kc = cntk;
    int kcc = kc < KPG ? kc : KPG;
    if (t == 0) {
        out[G_GRAPHS + g] = (kc > 0) ? red[0] / (float)kc : 0.f;
        kcnt[g] = kcc;
    }
    for (int i = t; i < kcc; i += 256) {
        int n = ns + lst[i];
        klist[g * KPG + i] = n;
        atomicOr(&kept_bits[n >> 5], 1u << (n & 31));
    }
    __syncthreads();
    for (int j = t; j < kcc * H_DIM; j += 256)
        B[(size_t)(ns + lst[j >> 6]) * H_DIM + (j & 63)] = 0.f;
}

// wave-ballot list emit: one global atomic per wave-with-hits (rare both-kept edges only)
__device__ __forceinline__ void emit(bool hit, int s, int d, int* __restrict__ list,
                                     int cap, int* __restrict__ count, int lane) {
    unsigned long long bal = __ballot(hit);
    if (bal == 0ull) return;
    int leader = __ffsll((long long)bal) - 1;
    int cnt = __popcll(bal);
    int base = 0;
    if (lane == leader) base = atomicAdd(count, cnt);
    base = __shfl(base, leader, 64);
    if (hit) {
        int p = base + __popcll(bal & ((1ull << lane) - 1ull));
        if (p < cap) { list[p] = s; list[cap + p] = d; }
    }
}

// ---------- fused edge scan + layer-1 agg: detect FIRST, stage W1 only if hits ----------
__global__ void k5f2(const int* __restrict__ ei, const unsigned int* __restrict__ bits,
                     const float* __restrict__ x, const float* __restrict__ W1,
                     float* __restrict__ B, int* __restrict__ elsd,
                     int* __restrict__ elcount) {
    __shared__ float W1s[C_IN * H_DIM];   // 32 KB (staged lazily)
    __shared__ int ls[1024], ld[1024];    // 8 KB
    __shared__ int c1;
    const int t = threadIdx.x;
    const int lane = t & 63;
    if (t == 0) c1 = 0;
    // detection: 4 edges/thread via int4 (issued immediately, no staging first)
    int t4 = blockIdx.x * 256 + t;
    bool valid = t4 < (N_EDGES / 4);
    int4 s4 = make_int4(0, 0, 0, 0), d4 = make_int4(0, 0, 0, 0);
    if (valid) {
        s4 = ((const int4*)ei)[t4];
        d4 = ((const int4*)(ei + N_EDGES))[t4];
    }
    __syncthreads();  // c1 = 0 visible
    int sv[4] = {s4.x, s4.y, s4.z, s4.w};
    int dv[4] = {d4.x, d4.y, d4.z, d4.w};
    bool bk[4];
    #pragma unroll
    for (int q = 0; q < 4; ++q) {
        int ss = sv[q], dd = dv[q];
        bool kd = valid && (((bits[dd >> 5] >> (dd & 31)) & 1u) != 0u);
        bk[q] = kd && (((bits[ss >> 5] >> (ss & 31)) & 1u) != 0u);
        if (kd) { int p = atomicAdd(&c1, 1); ls[p] = ss; ld[p] = dd; }
    }
    #pragma unroll
    for (int q = 0; q < 4; ++q) emit(bk[q], sv[q], dv[q], elsd, ELCAP, elcount, lane);
    __syncthreads();
    const int nloc = c1;
    if (nloc == 0) return;  // ~96% of blocks exit here without touching W1
    // stage W1 only in blocks that need it
    for (int i = t; i < C_IN * H_DIM; i += 256) W1s[i] = W1[i];
    __syncthreads();
    // consume: wave per hit-edge, lane = output channel
    const int w = t >> 6;
    for (int idx = w; idx < nloc; idx += 4) {
        int s = ls[idx];
        int d = ld[idx];
        const float4* xr = (const float4*)(x + (size_t)s * C_IN);
        float acc = 0.f;
        #pragma unroll 8
        for (int k4 = 0; k4 < C_IN / 4; ++k4) {
            float4 xv = xr[k4];
            acc = fmaf(xv.x, W1s[(4 * k4 + 0) * H_DIM + lane], acc);
            acc = fmaf(xv.y, W1s[(4 * k4 + 1) * H_DIM + lane], acc);
            acc = fmaf(xv.z, W1s[(4 * k4 + 2) * H_DIM + lane], acc);
            acc = fmaf(xv.w, W1s[(4 * k4 + 3) * H_DIM + lane], acc);
        }
        atomicAdd(&B[(size_t)d * H_DIM + lane], acc);
    }
}

// ---------- one wave per graph: layer-1 MLP + W3 projection for kept nodes ----------
// Weights read from global (L2-resident, tiny aggregate traffic); no LDS, no slot scan.
__global__ void k6w(const int* __restrict__ klist, const int* __restrict__ kcnt,
                    const float* __restrict__ sc, const float* __restrict__ x,
                    const float* __restrict__ W1,
                    const float* __restrict__ b1, const float* __restrict__ W2,
                    const float* __restrict__ b2, const float* __restrict__ W3,
                    float* __restrict__ A, float* __restrict__ B) {
    const int g = blockIdx.x;
    const int lane = threadIdx.x;  // 64 threads
    const int kc = kcnt[g];
    const float b1l = b1[lane], b2l = b2[lane];
    for (int i = 0; i < kc; ++i) {
        int n = __builtin_amdgcn_readfirstlane(klist[g * KPG + i]);
        const float4* xr = (const float4*)(x + (size_t)n * C_IN);
        float u = 0.f;
        #pragma unroll 8
        for (int k4 = 0; k4 < C_IN / 4; ++k4) {
            float4 xv = xr[k4];
            u = fmaf(xv.x, W1[(4 * k4 + 0) * H_DIM + lane], u);
            u = fmaf(xv.y, W1[(4 * k4 + 1) * H_DIM + lane], u);
            u = fmaf(xv.z, W1[(4 * k4 + 2) * H_DIM + lane], u);
            u = fmaf(xv.w, W1[(4 * k4 + 3) * H_DIM + lane], u);
        }
        float t1 = fmaxf(u + B[(size_t)n * H_DIM + lane] + b1l, 0.f);
        B[(size_t)n * H_DIM + lane] = 0.f;  // reset for layer-2 agg
        float o1 = b2l;
        #pragma unroll 8
        for (int k = 0; k < H_DIM; ++k) o1 = fmaf(__shfl(t1, k, 64), W2[k * H_DIM + lane], o1);
        o1 = fmaxf(o1, 0.f);
        float v = 0.f;
        #pragma unroll 8
        for (int k = 0; k < H_DIM; ++k) v = fmaf(__shfl(o1, k, 64), W3[k * H_DIM + lane], v);
        A[(size_t)n * H_DIM + lane] = v * sc[n];
    }
}

// ---------- layer-2 agg over both-kept edges ----------
__global__ void k7_scatter2(const int* __restrict__ elsd, const int* __restrict__ elcount,
                            const float* __restrict__ A, float* __restrict__ B) {
    const int lane = threadIdx.x & 63;
    const int wid  = blockIdx.x * (blockDim.x >> 6) + (threadIdx.x >> 6);
    const int nw   = gridDim.x * (blockDim.x >> 6);
    int ec = *elcount; if (ec > ELCAP) ec = ELCAP;
    for (int idx = wid; idx < ec; idx += nw) {
        int s = __builtin_amdgcn_readfirstlane(elsd[idx]);
        int d = __builtin_amdgcn_readfirstlane(elsd[ELCAP + idx]);
        atomicAdd(&B[(size_t)d * H_DIM + lane], A[(size_t)s * H_DIM + lane]);
    }
}

// ---------- one wave per graph: layer-2 MLP + pool + pred + ratio ----------
__global__ void k8b(const int* __restrict__ klist, const int* __restrict__ kcnt,
                    const float* __restrict__ b3, const float* __restrict__ W4,
                    const float* __restrict__ b4, const float* __restrict__ Wl,
                    const float* __restrict__ bl,
                    const float* __restrict__ A, const float* __restrict__ B,
                    float* __restrict__ out) {
    const int g = blockIdx.x;
    const int lane = threadIdx.x;  // 64 threads
    const float b3l = b3[lane], b4l = b4[lane];
    const int kc = kcnt[g];
    float gsum = 0.f;
    for (int i = 0; i < kc; ++i) {
        int n = __builtin_amdgcn_readfirstlane(klist[g * KPG + i]);
        float t = fmaxf(A[(size_t)n * H_DIM + lane] + B[(size_t)n * H_DIM + lane] + b3l, 0.f);
        float o2 = b4l;
        #pragma unroll 8
        for (int k = 0; k < H_DIM; ++k) o2 = fmaf(__shfl(t, k, 64), W4[k * H_DIM + lane], o2);
        gsum += fmaxf(o2, 0.f);
    }
    float p = gsum * Wl[lane];
    #pragma unroll
    for (int m = 32; m > 0; m >>= 1) p += __shfl_xor(p, m, 64);
    if (lane == 0) out[g] = p + bl[0];
    if (g == 0) {
        int tot = 0;
        for (int i = lane; i < G_GRAPHS; i += 64) tot += kcnt[i];
        #pragma unroll
        for (int m = 32; m > 0; m >>= 1) tot += __shfl_xor(tot, m, 64);
        if (lane == 0) out[2 * G_GRAPHS] = (float)tot * (1.f / (float)N_NODES);
    }
}

extern "C" void kernel_launch(void* const* d_in, const int* in_sizes, int n_in,
                              void* d_out, int out_size, void* d_ws, size_t ws_size,
                              hipStream_t stream) {
    const float* x      = (const float*)d_in[0];
    const int*   ei     = (const int*)d_in[1];
    const int*   batch  = (const int*)d_in[2];
    const float* attn   = (const float*)d_in[3];
    const float* W1     = (const float*)d_in[4];
    const float* b1     = (const float*)d_in[5];
    const float* W2     = (const float*)d_in[6];
    const float* b2     = (const float*)d_in[7];
    const float* pool_w = (const float*)d_in[8];
    const float* W3     = (const float*)d_in[9];
    const float* b3     = (const float*)d_in[10];
    const float* W4     = (const float*)d_in[11];
    const float* b4     = (const float*)d_in[12];
    const float* Wl     = (const float*)d_in[13];
    const float* bl     = (const float*)d_in[14];
    float* out = (float*)d_out;

    // workspace layout
    float* A      = (float*)d_ws;                       // N*64 (kept rows only used)
    float* B      = A + (size_t)N_NODES * H_DIM;        // N*64 (kept rows only used)
    float* sc     = B + (size_t)N_NODES * H_DIM;        // N: raw -> kept scores
    int*   klist  = (int*)(sc + N_NODES);               // G*KPG (per-graph strided)
    int*   kcnt   = klist + G_GRAPHS * KPG;             // G
    int*   elsd   = kcnt + G_GRAPHS;                    // 2*ELCAP
    // zeroed block:
    unsigned int* kept_bits = (unsigned int*)(elsd + 2 * ELCAP);   // ceil(N/32)=3125 -> 3136
    int*          elcount   = (int*)(kept_bits + 3136);
    size_t zero_bytes = (size_t)((char*)(elcount + 1) - (char*)kept_bits);

    hipMemsetAsync(kept_bits, 0, zero_bytes, stream);

    kraw <<<2048, 256, 0, stream>>>(x, pool_w, sc);
    kA3  <<<G_GRAPHS, 256, 0, stream>>>(batch, attn, sc, kept_bits, klist, kcnt, B, out);
    k5f2 <<<(N_EDGES / 4 + 255) / 256, 256, 0, stream>>>(ei, kept_bits, x, W1, B,
                                                         elsd, elcount);
    k6w  <<<G_GRAPHS, 64, 0, stream>>>(klist, kcnt, sc, x, W1, b1, W2, b2, W3, A, B);
    k7_scatter2<<<32, 256, 0, stream>>>(elsd, elcount, A, B);
    k8b  <<<G_GRAPHS, 64, 0, stream>>>(klist, kcnt, b3, W4, b4, Wl, bl, A, B, out);
}

// Round 8
// 174.927 us; speedup vs baseline: 1.6725x; 1.0507x over previous
//
#include <hip/hip_runtime.h>
#include <math.h>

#define N_NODES 100000
#define N_EDGES 1600000
#define C_IN    128
#define H_DIM   64
#define G_GRAPHS 512
#define MAXG    4096      // max nodes/graph in kA4 LDS (mean 195, huge margin)
#define ELCAP   65536     // both-kept edge list cap (expected ~tens)
#define KPG     32        // kept-per-graph cap (math bound: scores sum to 1, thresh 0.05 -> <=19)
#define NBITS   3136      // ceil(N/32) rounded up

// lower_bound over sorted batch
__device__ __forceinline__ int lbound(const int* __restrict__ b, int val) {
    int lo = 0, hi = N_NODES;
    while (lo < hi) {
        int mid = (lo + hi) >> 1;
        if (b[mid] < val) lo = mid + 1; else hi = mid;
    }
    return lo;
}

// ---------- raw = x . pool_w (pure BW) + zero bits/elcount ----------
__global__ void kpre(const float* __restrict__ x, const float* __restrict__ pool_w,
                     float* __restrict__ sc, unsigned int* __restrict__ zero_region) {
    int gid = blockIdx.x * blockDim.x + threadIdx.x;
    if (gid < NBITS + 1) zero_region[gid] = 0u;   // kept_bits + elcount
    const int lane = threadIdx.x & 63;
    const int l32  = lane & 31;
    const int half = lane >> 5;
    const float4 pwv = ((const float4*)pool_w)[l32];
    const int wid = blockIdx.x * (blockDim.x >> 6) + (threadIdx.x >> 6);
    const int nw  = gridDim.x * (blockDim.x >> 6);
    // unroll x2: two row-pairs in flight per iteration (N divisible by 4)
    for (int r0 = wid * 4; r0 < N_NODES; r0 += nw * 4) {
        int rowA = r0 + half;
        int rowB = r0 + 2 + half;
        float4 xa = ((const float4*)(x + (size_t)rowA * C_IN))[l32];
        float4 xb = ((const float4*)(x + (size_t)rowB * C_IN))[l32];
        float pa = xa.x * pwv.x + xa.y * pwv.y + xa.z * pwv.z + xa.w * pwv.w;
        float pb = xb.x * pwv.x + xb.y * pwv.y + xb.z * pwv.z + xb.w * pwv.w;
        #pragma unroll
        for (int m = 16; m > 0; m >>= 1) {
            pa += __shfl_xor(pa, m, 64);
            pb += __shfl_xor(pb, m, 64);
        }
        if (l32 == 0) { sc[rowA] = pa; sc[rowB] = pb; }
    }
}

// block reductions for 256-thread (4-wave) blocks, shuffle + 4-slot LDS
__device__ __forceinline__ float blk_max(float v, float* red, int lane, int w) {
    #pragma unroll
    for (int m = 32; m > 0; m >>= 1) v = fmaxf(v, __shfl_xor(v, m, 64));
    if (lane == 0) red[w] = v;
    __syncthreads();
    float r = fmaxf(fmaxf(red[0], red[1]), fmaxf(red[2], red[3]));
    __syncthreads();
    return r;
}
__device__ __forceinline__ float blk_sum(float v, float* red, int lane, int w) {
    #pragma unroll
    for (int m = 32; m > 0; m >>= 1) v += __shfl_xor(v, m, 64);
    if (lane == 0) red[w] = v;
    __syncthreads();
    float r = (red[0] + red[1]) + (red[2] + red[3]);
    __syncthreads();
    return r;
}

// ---------- per-graph softmax + mask + KL + compaction (2 reductions, smax=1/z) ----------
__global__ void kA4(const int* __restrict__ batch, const float* __restrict__ attn,
                    float* __restrict__ sc, unsigned int* __restrict__ kept_bits,
                    int* __restrict__ klist, int* __restrict__ kcnt,
                    float* __restrict__ B, float* __restrict__ out) {
    __shared__ float buf[MAXG];
    __shared__ float red[4];
    __shared__ int   lst[KPG];
    __shared__ int   cntk;
    const int g = blockIdx.x;
    const int t = threadIdx.x;
    const int lane = t & 63;
    const int w = t >> 6;
    const int ns = lbound(batch, g);
    const int ne = lbound(batch, g + 1);
    const int cn = ne - ns;
    if (cn <= 0) {
        if (t == 0) { out[G_GRAPHS + g] = 0.f; kcnt[g] = 0; }
        return;
    }
    if (t == 0) cntk = 0;
    float lmax = -3.4e38f;
    for (int i = t; i < cn; i += 256) { float r = sc[ns + i]; buf[i] = r; lmax = fmaxf(lmax, r); }
    float m = blk_max(lmax, red, lane, w);
    float lsum = 0.f;
    for (int i = t; i < cn; i += 256) { float e = expf(buf[i] - m); buf[i] = e; lsum += e; }
    float z = blk_sum(lsum, red, lane, w);
    // smax = exp(m - m)/z = 1/z exactly (same rounding as reference's max(e)/z)
    float thresh = fminf(1.f / z - 1e-7f, 0.05f);
    // kept compaction + KL
    float klacc = 0.f;
    for (int i = t; i < cn; i += 256) {
        float s = buf[i] / z;
        if (s > thresh) {
            int n = ns + i;
            int p = atomicAdd(&cntk, 1);
            if (p < KPG) lst[p] = i;
            sc[n] = s;
            float a = attn[n];
            klacc += a * (logf(a) - logf(s + 1e-14f));
        }
    }
    float klsum = blk_sum(klacc, red, lane, w);   // syncs also make cntk/lst visible
    int kct = cntk;
    int kc = kct < KPG ? kct : KPG;
    if (t == 0) {
        out[G_GRAPHS + g] = (kct > 0) ? klsum / (float)kct : 0.f;
        kcnt[g] = kc;
    }
    for (int i = t; i < kc; i += 256) {
        int n = ns + lst[i];
        klist[g * KPG + i] = n;
        atomicOr(&kept_bits[n >> 5], 1u << (n & 31));
    }
    for (int j = t; j < kc * H_DIM; j += 256)
        B[(size_t)(ns + lst[j >> 6]) * H_DIM + (j & 63)] = 0.f;
}

// wave-ballot list emit: one global atomic per wave-with-hits (rare both-kept edges only)
__device__ __forceinline__ void emit(bool hit, int s, int d, int* __restrict__ list,
                                     int cap, int* __restrict__ count, int lane) {
    unsigned long long bal = __ballot(hit);
    if (bal == 0ull) return;
    int leader = __ffsll((long long)bal) - 1;
    int cnt = __popcll(bal);
    int base = 0;
    if (lane == leader) base = atomicAdd(count, cnt);
    base = __shfl(base, leader, 64);
    if (hit) {
        int p = base + __popcll(bal & ((1ull << lane) - 1ull));
        if (p < cap) { list[p] = s; list[cap + p] = d; }
    }
}

// ---------- fused edge scan + layer-1 agg: detect first, stage W1 only if hits ----------
__global__ void k5f2(const int* __restrict__ ei, const unsigned int* __restrict__ bits,
                     const float* __restrict__ x, const float* __restrict__ W1,
                     float* __restrict__ B, int* __restrict__ elsd,
                     int* __restrict__ elcount) {
    __shared__ float W1s[C_IN * H_DIM];   // 32 KB (staged lazily)
    __shared__ int ls[1024], ld[1024];    // 8 KB
    __shared__ int c1;
    const int t = threadIdx.x;
    const int lane = t & 63;
    if (t == 0) c1 = 0;
    int t4 = blockIdx.x * 256 + t;
    bool valid = t4 < (N_EDGES / 4);
    int4 s4 = make_int4(0, 0, 0, 0), d4 = make_int4(0, 0, 0, 0);
    if (valid) {
        s4 = ((const int4*)ei)[t4];
        d4 = ((const int4*)(ei + N_EDGES))[t4];
    }
    __syncthreads();  // c1 = 0 visible
    int sv[4] = {s4.x, s4.y, s4.z, s4.w};
    int dv[4] = {d4.x, d4.y, d4.z, d4.w};
    bool bk[4];
    #pragma unroll
    for (int q = 0; q < 4; ++q) {
        int ss = sv[q], dd = dv[q];
        bool kd = valid && (((bits[dd >> 5] >> (dd & 31)) & 1u) != 0u);
        bk[q] = kd && (((bits[ss >> 5] >> (ss & 31)) & 1u) != 0u);
        if (kd) { int p = atomicAdd(&c1, 1); ls[p] = ss; ld[p] = dd; }
    }
    #pragma unroll
    for (int q = 0; q < 4; ++q) emit(bk[q], sv[q], dv[q], elsd, ELCAP, elcount, lane);
    __syncthreads();
    const int nloc = c1;
    if (nloc == 0) return;  // ~96% of blocks exit without touching W1
    for (int i = t; i < C_IN * H_DIM; i += 256) W1s[i] = W1[i];
    __syncthreads();
    const int w = t >> 6;
    for (int idx = w; idx < nloc; idx += 4) {
        int s = ls[idx];
        int d = ld[idx];
        const float4* xr = (const float4*)(x + (size_t)s * C_IN);
        float acc = 0.f;
        #pragma unroll 8
        for (int k4 = 0; k4 < C_IN / 4; ++k4) {
            float4 xv = xr[k4];
            acc = fmaf(xv.x, W1s[(4 * k4 + 0) * H_DIM + lane], acc);
            acc = fmaf(xv.y, W1s[(4 * k4 + 1) * H_DIM + lane], acc);
            acc = fmaf(xv.z, W1s[(4 * k4 + 2) * H_DIM + lane], acc);
            acc = fmaf(xv.w, W1s[(4 * k4 + 3) * H_DIM + lane], acc);
        }
        atomicAdd(&B[(size_t)d * H_DIM + lane], acc);
    }
}

// compute channel `lane` of A[n] = score[n] * (relu(relu(x[n]@W1 + B[n] + b1)@W2 + b2)@W3)
// wave-uniform n; must be called by all 64 lanes.
__device__ __forceinline__ float computeA(int n, int lane,
                                          const float* __restrict__ x,
                                          const float* __restrict__ B,
                                          const float* __restrict__ sc,
                                          const float* __restrict__ W1, float b1l,
                                          const float* __restrict__ W2, float b2l,
                                          const float* __restrict__ W3) {
    const float4* xr = (const float4*)(x + (size_t)n * C_IN);
    float u = 0.f;
    #pragma unroll 8
    for (int k4 = 0; k4 < C_IN / 4; ++k4) {
        float4 xv = xr[k4];
        u = fmaf(xv.x, W1[(4 * k4 + 0) * H_DIM + lane], u);
        u = fmaf(xv.y, W1[(4 * k4 + 1) * H_DIM + lane], u);
        u = fmaf(xv.z, W1[(4 * k4 + 2) * H_DIM + lane], u);
        u = fmaf(xv.w, W1[(4 * k4 + 3) * H_DIM + lane], u);
    }
    float t1 = fmaxf(u + B[(size_t)n * H_DIM + lane] + b1l, 0.f);
    float o1 = b2l;
    #pragma unroll 8
    for (int k = 0; k < H_DIM; ++k) o1 = fmaf(__shfl(t1, k, 64), W2[k * H_DIM + lane], o1);
    o1 = fmaxf(o1, 0.f);
    float v = 0.f;
    #pragma unroll 8
    for (int k = 0; k < H_DIM; ++k) v = fmaf(__shfl(o1, k, 64), W3[k * H_DIM + lane], v);
    return v * sc[n];
}

// ---------- one wave per graph: layer-1 MLP (on demand) + layer-2 agg (elsd gather)
//            + layer-2 MLP + pool + pred + ratio ----------
__global__ void k8c(const int* __restrict__ klist, const int* __restrict__ kcnt,
                    const float* __restrict__ sc, const float* __restrict__ x,
                    const float* __restrict__ W1, const float* __restrict__ b1,
                    const float* __restrict__ W2, const float* __restrict__ b2,
                    const float* __restrict__ W3, const float* __restrict__ b3,
                    const float* __restrict__ W4, const float* __restrict__ b4,
                    const float* __restrict__ Wl, const float* __restrict__ bl,
                    const float* __restrict__ B, const int* __restrict__ elsd,
                    const int* __restrict__ elcount, float* __restrict__ out) {
    const int g = blockIdx.x;
    const int lane = threadIdx.x;  // 64 threads
    const float b1l = b1[lane], b2l = b2[lane], b3l = b3[lane], b4l = b4[lane];
    const int kc = kcnt[g];
    int ec = *elcount; if (ec > ELCAP) ec = ELCAP;
    float gsum = 0.f;
    for (int i = 0; i < kc; ++i) {
        int n = __builtin_amdgcn_readfirstlane(klist[g * KPG + i]);
        // layer-2 aggregation: gather A[src] for both-kept edges with dst == n
        float agg = 0.f;
        for (int base = 0; base < ec; base += 64) {
            int idx = base + lane;
            int dd = (idx < ec) ? elsd[ELCAP + idx] : -1;
            bool mtc = (dd == n);
            int ssl = mtc ? elsd[idx] : 0;
            unsigned long long bal = __ballot(mtc);
            while (bal) {
                int j = __ffsll((long long)bal) - 1;
                bal &= bal - 1;
                int s = __builtin_amdgcn_readfirstlane(__shfl(ssl, j, 64));
                agg += computeA(s, lane, x, B, sc, W1, b1l, W2, b2l, W3);
            }
        }
        float vA = computeA(n, lane, x, B, sc, W1, b1l, W2, b2l, W3);
        float t = fmaxf(vA + agg + b3l, 0.f);
        float o2 = b4l;
        #pragma unroll 8
        for (int k = 0; k < H_DIM; ++k) o2 = fmaf(__shfl(t, k, 64), W4[k * H_DIM + lane], o2);
        gsum += fmaxf(o2, 0.f);
    }
    float p = gsum * Wl[lane];
    #pragma unroll
    for (int m = 32; m > 0; m >>= 1) p += __shfl_xor(p, m, 64);
    if (lane == 0) out[g] = p + bl[0];
    if (g == 0) {
        int tot = 0;
        for (int i = lane; i < G_GRAPHS; i += 64) tot += kcnt[i];
        #pragma unroll
        for (int m = 32; m > 0; m >>= 1) tot += __shfl_xor(tot, m, 64);
        if (lane == 0) out[2 * G_GRAPHS] = (float)tot * (1.f / (float)N_NODES);
    }
}

extern "C" void kernel_launch(void* const* d_in, const int* in_sizes, int n_in,
                              void* d_out, int out_size, void* d_ws, size_t ws_size,
                              hipStream_t stream) {
    const float* x      = (const float*)d_in[0];
    const int*   ei     = (const int*)d_in[1];
    const int*   batch  = (const int*)d_in[2];
    const float* attn   = (const float*)d_in[3];
    const float* W1     = (const float*)d_in[4];
    const float* b1     = (const float*)d_in[5];
    const float* W2     = (const float*)d_in[6];
    const float* b2     = (const float*)d_in[7];
    const float* pool_w = (const float*)d_in[8];
    const float* W3     = (const float*)d_in[9];
    const float* b3     = (const float*)d_in[10];
    const float* W4     = (const float*)d_in[11];
    const float* b4     = (const float*)d_in[12];
    const float* Wl     = (const float*)d_in[13];
    const float* bl     = (const float*)d_in[14];
    float* out = (float*)d_out;

    // workspace layout
    float* B      = (float*)d_ws;                       // N*64 (kept rows only used)
    float* sc     = B + (size_t)N_NODES * H_DIM;        // N: raw -> kept scores
    int*   klist  = (int*)(sc + N_NODES);               // G*KPG (per-graph strided)
    int*   kcnt   = klist + G_GRAPHS * KPG;             // G
    int*   elsd   = kcnt + G_GRAPHS;                    // 2*ELCAP
    unsigned int* kept_bits = (unsigned int*)(elsd + 2 * ELCAP);   // NBITS
    int*          elcount   = (int*)(kept_bits + NBITS);           // 1 (zeroed with bits)

    kpre <<<2048, 256, 0, stream>>>(x, pool_w, sc, kept_bits);
    kA4  <<<G_GRAPHS, 256, 0, stream>>>(batch, attn, sc, kept_bits, klist, kcnt, B, out);
    k5f2 <<<(N_EDGES / 4 + 255) / 256, 256, 0, stream>>>(ei, kept_bits, x, W1, B,
                                                         elsd, elcount);
    k8c  <<<G_GRAPHS, 64, 0, stream>>>(klist, kcnt, sc, x, W1, b1, W2, b2, W3, b3,
                                       W4, b4, Wl, bl, B, elsd, elcount, out);
}